// Round 9
// baseline (3331.201 us; speedup 1.0000x reference)
//
#include <hip/hip_runtime.h>
#include <hip/hip_bf16.h>
#include <stdint.h>

#define T_SEQ 128
#define NBATCH 32
#define EMBED 512
#define HID 1024
#define NVOCAB 32000
#define NBLK 256
#define NTILE 32000          // 64 x 500 logits tiles of 64x64
#define TSTRIDE 1024         // tiles strided by total wave count (256 blk x 4 waves)

typedef float f32x4 __attribute__((ext_vector_type(4)));
typedef _Float16 f16x8 __attribute__((ext_vector_type(8)));

__device__ __forceinline__ unsigned short f2h(float f) {
  _Float16 h = (_Float16)f;
  return __builtin_bit_cast(unsigned short, h);
}
__device__ __forceinline__ float sigm(float x) {
  return 1.0f / (1.0f + __expf(-x));
}
__device__ __forceinline__ float tanh_fast(float x) {
  return 2.0f / (1.0f + __expf(-2.0f * x)) - 1.0f;
}

// ---------------- zero the sync state ----------------
__global__ void k_zero(unsigned int* __restrict__ p, int n) {
  int i = blockIdx.x * blockDim.x + threadIdx.x;
  if (i < n) p[i] = 0;
}

// ---------------- f32 -> f16 convert (vectorized, grid-stride) ----------------
__global__ void k_f32_to_f16(const float4* __restrict__ in,
                             ushort4* __restrict__ out, int n4) {
  int i = blockIdx.x * blockDim.x + threadIdx.x;
  int stride = gridDim.x * blockDim.x;
  for (; i < n4; i += stride) {
    float4 v = in[i];
    ushort4 o;
    o.x = f2h(v.x); o.y = f2h(v.y); o.z = f2h(v.z); o.w = f2h(v.w);
    out[i] = o;
  }
}

// ------------- embedding gather -> A0 f16 [4096][512], row m = t*32+b -------------
__global__ void k_embed(const int* __restrict__ tok, const float* __restrict__ table,
                        ushort4* __restrict__ A0) {
  int tid = blockIdx.x * 256 + threadIdx.x;
  int m = tid >> 7, kq = tid & 127;
  int b = m & 31, t = m >> 5;
  int tk = tok[b * T_SEQ + t];
  float4 v = *(const float4*)(table + (size_t)tk * EMBED + kq * 4);
  ushort4 o;
  o.x = f2h(v.x); o.y = f2h(v.y); o.z = f2h(v.z); o.w = f2h(v.w);
  A0[tid] = o;
}

// ---------------- f16 MFMA GEMM (reg-staged; used only for gi0) ----------------
#define BM 128
#define BN 128
#define BKK 64

__global__ __launch_bounds__(256) void k_gemm_bt(
    const short* __restrict__ A, const short* __restrict__ B,
    float* __restrict__ C, const float* __restrict__ bias,
    int M, int N, int K, int permute)
{
  __shared__ __align__(16) short As[BM * BKK];
  __shared__ __align__(16) short Bs[BN * BKK];
  const int tid = threadIdx.x;
  const int w = tid >> 6, l = tid & 63;
  const int wr = w >> 1, wc = w & 1;
  const int bm = blockIdx.x * BM, bn = blockIdx.y * BN;
  const int l15 = l & 15, lkg = l >> 4;

  f32x4 acc[4][4] = {};

  for (int kt = 0; kt < K; kt += BKK) {
#pragma unroll
    for (int p = 0; p < 4; ++p) {
      int idx = p * 2048 + tid * 8;
      int r = idx >> 6, c = idx & 63;
      *(f16x8*)&As[idx] = *(const f16x8*)&A[(size_t)(bm + r) * K + kt + c];
      *(f16x8*)&Bs[idx] = *(const f16x8*)&B[(size_t)(bn + r) * K + kt + c];
    }
    __syncthreads();

#pragma unroll
    for (int ks = 0; ks < 2; ++ks) {
      f16x8 af[4], bfr[4];
#pragma unroll
      for (int mi = 0; mi < 4; ++mi)
        af[mi] = *(const f16x8*)&As[(wr * 64 + mi * 16 + l15) * BKK + ks * 32 + lkg * 8];
#pragma unroll
      for (int ni = 0; ni < 4; ++ni)
        bfr[ni] = *(const f16x8*)&Bs[(wc * 64 + ni * 16 + l15) * BKK + ks * 32 + lkg * 8];
#pragma unroll
      for (int mi = 0; mi < 4; ++mi)
#pragma unroll
        for (int ni = 0; ni < 4; ++ni)
          acc[mi][ni] = __builtin_amdgcn_mfma_f32_16x16x32_f16(
              af[mi], bfr[ni], acc[mi][ni], 0, 0, 0);
    }
    __syncthreads();
  }

  const int lr = lkg * 4;
#pragma unroll
  for (int mi = 0; mi < 4; ++mi) {
#pragma unroll
    for (int ni = 0; ni < 4; ++ni) {
      int col = bn + wc * 64 + ni * 16 + l15;
      float bv = bias ? bias[col] : 0.0f;
#pragma unroll
      for (int j = 0; j < 4; ++j) {
        int row = bm + wr * 64 + mi * 16 + lr + j;
        int orow = permute ? ((row & 31) * T_SEQ + (row >> 5)) : row;
        C[(size_t)orow * N + col] = acc[mi][ni][j] + bv;
      }
    }
  }
}

// ======== fused: 2-layer GRU recurrence + logits GEMM in idle waves ========
// 256 blocks x 256 threads (4 waves). Wave w: isHH=w>>1 (0: layer-0 W_hh0;
// 1: merged layer-1 W_ih1+W_hh1), nt=w&1 (batch half). Block owns j in
// [4*bid,4*bid+4). No __syncthreads in the loop — waves fully decoupled.
// Sync: per-wave flags (64B-padded) -> block-0-wave-0 sequencer -> 64 epoch
// replicas (round-8 proven protocol, coupled exit => epoch1 always published).
// Idle waves compute 64x64 logits tiles (m̂-major, strided by 1024), gated by
// epoch1 >= 2*m̂+2 (ys1f rows final). Epilogue: permute row->b*128+t, +bias.
__global__ __launch_bounds__(256, 1) void k_gru_fused(
    const float* __restrict__ gi0,
    const float* __restrict__ Whh0, const float* __restrict__ bhh0,
    const float* __restrict__ Wih1, const float* __restrict__ bih1,
    const float* __restrict__ Whh1, const float* __restrict__ bhh1,
    const _Float16* __restrict__ h0i, const _Float16* __restrict__ h1i,
    _Float16* __restrict__ ys0f, _Float16* __restrict__ ys1f,
    const short* __restrict__ B2,   // [32000][1024] f16 (W_out)
    const float* __restrict__ bout, float* __restrict__ out,
    unsigned int* flg0, unsigned int* flg1,     // [512*16]
    unsigned int* epoch0, unsigned int* epoch1) // [64*16]
{
  const int tid = threadIdx.x;
  const int l = tid & 63;
  const int w = tid >> 6;
  const int bid = blockIdx.x;
  const int isHH = w >> 1, nt = w & 1;
  const int j0 = bid * 4;

  const int row16 = l & 15;
  const int jjr = row16 >> 2, gate = row16 & 3;
  const int koct = l >> 4;
  const int b_out = nt * 16 + row16;
  const int j_out = j0 + (l >> 4);
  const int jj_even = (((l >> 4) & 1) == 0);
  const int bfragOff = b_out * 2048 + koct * 16;
  const bool isSeq = (bid == 0 && w == 0);

  // ---- weights in registers ----
  f16x8 afA[32];   // role0: Whh0 ; role12: Wih1
  f16x8 afB[32];   // role12 only: Whh1
  {
    const float* WsrcA = isHH ? Wih1 : Whh0;
    if (gate < 3) {
      const float* wrow = WsrcA + (size_t)(gate * HID + j0 + jjr) * HID;
#pragma unroll
      for (int c = 0; c < 32; ++c) {
        float4 p0 = *(const float4*)(wrow + c * 32 + koct * 8);
        float4 p1 = *(const float4*)(wrow + c * 32 + koct * 8 + 4);
        f16x8 v = { (_Float16)p0.x, (_Float16)p0.y, (_Float16)p0.z, (_Float16)p0.w,
                    (_Float16)p1.x, (_Float16)p1.y, (_Float16)p1.z, (_Float16)p1.w };
        afA[c] = v;
      }
    } else {
#pragma unroll
      for (int c = 0; c < 32; ++c) {
        f16x8 z = { (_Float16)0.f,(_Float16)0.f,(_Float16)0.f,(_Float16)0.f,
                    (_Float16)0.f,(_Float16)0.f,(_Float16)0.f,(_Float16)0.f };
        afA[c] = z;
      }
    }
    if (isHH) {
      if (gate < 3) {
        const float* wrow = Whh1 + (size_t)(gate * HID + j0 + jjr) * HID;
#pragma unroll
        for (int c = 0; c < 32; ++c) {
          float4 p0 = *(const float4*)(wrow + c * 32 + koct * 8);
          float4 p1 = *(const float4*)(wrow + c * 32 + koct * 8 + 4);
          f16x8 v = { (_Float16)p0.x, (_Float16)p0.y, (_Float16)p0.z, (_Float16)p0.w,
                      (_Float16)p1.x, (_Float16)p1.y, (_Float16)p1.z, (_Float16)p1.w };
          afB[c] = v;
        }
      } else {
#pragma unroll
        for (int c = 0; c < 32; ++c) {
          f16x8 z = { (_Float16)0.f,(_Float16)0.f,(_Float16)0.f,(_Float16)0.f,
                      (_Float16)0.f,(_Float16)0.f,(_Float16)0.f,(_Float16)0.f };
          afB[c] = z;
        }
      }
    }
  }

  // ---- biases ----
  float bR, bZ, bN, biR = 0.f, biZ = 0.f, biN = 0.f;
  if (!isHH) {
    bR = bhh0[j_out]; bZ = bhh0[HID + j_out]; bN = bhh0[2 * HID + j_out];
  } else {
    bR = bhh1[j_out]; bZ = bhh1[HID + j_out]; bN = bhh1[2 * HID + j_out];
    biR = bih1[j_out]; biZ = bih1[HID + j_out]; biN = bih1[2 * HID + j_out];
  }

  // ---- logits-GEMM state ----
  int tileT = bid * 4 + w;
  int kc = 0;
  f32x4 gacc[4][4] = {};
  const unsigned* ep0 = epoch0 + (bid & 63) * 16;
  const unsigned* ep1 = epoch1 + (bid & 63) * 16;
  const short* ysA = (const short*)ys1f;

  auto gemm_chunk = [&]() {
    int mh = tileT / 500, nh = tileT - mh * 500;
    int rowBase = mh * 64, colBase = nh * 64;
    int kk = kc * 64;
#pragma unroll
    for (int ks = 0; ks < 2; ++ks) {
      f16x8 a4[4], b4[4];
#pragma unroll
      for (int mi = 0; mi < 4; ++mi)
        a4[mi] = *(const f16x8*)&ysA[(size_t)(rowBase + mi * 16 + row16) * HID + kk + ks * 32 + koct * 8];
#pragma unroll
      for (int ni = 0; ni < 4; ++ni)
        b4[ni] = *(const f16x8*)&B2[(size_t)(colBase + ni * 16 + row16) * HID + kk + ks * 32 + koct * 8];
#pragma unroll
      for (int mi = 0; mi < 4; ++mi)
#pragma unroll
        for (int ni = 0; ni < 4; ++ni)
          gacc[mi][ni] = __builtin_amdgcn_mfma_f32_16x16x32_f16(
              a4[mi], b4[ni], gacc[mi][ni], 0, 0, 0);
    }
    ++kc;
    if (kc == 16) {
      const int lr = koct * 4;
#pragma unroll
      for (int mi = 0; mi < 4; ++mi)
#pragma unroll
        for (int ni = 0; ni < 4; ++ni) {
          int col = colBase + ni * 16 + row16;
          float bv = bout[col];
#pragma unroll
          for (int j = 0; j < 4; ++j) {
            int row = rowBase + mi * 16 + lr + j;
            int orow = (row & 31) * T_SEQ + (row >> 5);
            out[(size_t)orow * NVOCAB + col] = gacc[mi][ni][j] + bv;
          }
          gacc[mi][ni] = (f32x4){0.f, 0.f, 0.f, 0.f};
        }
      kc = 0;
      tileT += TSTRIDE;
    }
  };

  auto try_gemm = [&]() -> bool {
    if (tileT >= NTILE) return false;
    if (kc == 0) {
      int mh = tileT / 500;
      unsigned e = __hip_atomic_load(ep1, __ATOMIC_RELAXED, __HIP_MEMORY_SCOPE_AGENT);
      if (e < (unsigned)(2 * mh + 2)) return false;
      asm volatile("" ::: "memory");
    }
    gemm_chunk();
    return true;
  };

  // ================= main loop =================
  for (int s = 0; s <= T_SEQ; ++s) {
    // role-0 gi0 prefetch (flag-independent)
    float pre_ir = 0.f, pre_iz = 0.f, pre_in = 0.f;
    if (!isHH && s < T_SEQ) {
      const float* gib = gi0 + (size_t)(s * NBATCH + b_out) * 3072 + j_out;
      pre_ir = gib[0]; pre_iz = gib[HID]; pre_in = gib[2 * HID];
    }

    if (isSeq) {
      // sequencer (also role0 bid0/nt0): poll flags, publish epochs (coupled exit)
      unsigned t0 = (s >= 1) ? (unsigned)s : 0u;
      unsigned t1p = (s >= 2) ? (unsigned)(s - 1) : 0u;
      bool done0 = (t0 == 0u), done1 = (t1p == 0u);
      while (!(done0 && done1)) {
        if (!done0) {
          unsigned m0 = 0xffffffffu;
#pragma unroll
          for (int i = 0; i < 8; ++i) {
            unsigned v = __hip_atomic_load(flg0 + l * 128 + i * 16, __ATOMIC_RELAXED, __HIP_MEMORY_SCOPE_AGENT);
            m0 = v < m0 ? v : m0;
          }
          if (__all(m0 >= t0)) {
            __hip_atomic_store(epoch0 + l * 16, t0, __ATOMIC_RELAXED, __HIP_MEMORY_SCOPE_AGENT);
            done0 = true;
          }
        }
        if (!done1) {
          unsigned m1 = 0xffffffffu;
#pragma unroll
          for (int i = 0; i < 8; ++i) {
            unsigned v = __hip_atomic_load(flg1 + l * 128 + i * 16, __ATOMIC_RELAXED, __HIP_MEMORY_SCOPE_AGENT);
            m1 = v < m1 ? v : m1;
          }
          if (__all(m1 >= t1p)) {
            __hip_atomic_store(epoch1 + l * 16, t1p, __ATOMIC_RELAXED, __HIP_MEMORY_SCOPE_AGENT);
            done1 = true;
          }
        }
        if (!(done0 && done1)) {
          if (!try_gemm()) __builtin_amdgcn_s_sleep(2);
        }
      }
      asm volatile("" ::: "memory");
    } else {
      // workers: per-wave waits on epoch replicas, GEMM while spinning
      unsigned n0 = 0, n1 = 0;
      if (!isHH) { if (s >= 1 && s < T_SEQ) n0 = (unsigned)s; }
      else       { if (s >= 1) n0 = (unsigned)s; if (s >= 2) n1 = (unsigned)(s - 1); }
      if (n0) {
        while (__hip_atomic_load(ep0, __ATOMIC_RELAXED, __HIP_MEMORY_SCOPE_AGENT) < n0) {
          if (!try_gemm()) __builtin_amdgcn_s_sleep(2);
        }
      }
      if (n1) {
        while (__hip_atomic_load(ep1, __ATOMIC_RELAXED, __HIP_MEMORY_SCOPE_AGENT) < n1) {
          if (!try_gemm()) __builtin_amdgcn_s_sleep(2);
        }
      }
      asm volatile("" ::: "memory");
    }

    // ---------- role 0: layer-0 step t = s ----------
    if (!isHH && s < T_SEQ) {
      const _Float16* hsrc = (s == 0) ? h0i : (ys0f + (size_t)(s - 1) * NBATCH * HID);
      const char* hb = (const char*)hsrc + bfragOff;
      f32x4 acc0 = {}, acc1 = {};
#pragma unroll
      for (int c = 0; c < 32; c += 2) {
        f16x8 bf0 = *(const f16x8*)(hb + c * 64);
        f16x8 bf1 = *(const f16x8*)(hb + c * 64 + 64);
        acc0 = __builtin_amdgcn_mfma_f32_16x16x32_f16(afA[c], bf0, acc0, 0, 0, 0);
        acc1 = __builtin_amdgcn_mfma_f32_16x16x32_f16(afA[c + 1], bf1, acc1, 0, 0, 0);
      }
      f32x4 acc = acc0 + acc1;

      float hp = (float)((s == 0) ? h0i[b_out * HID + j_out]
                                  : ys0f[(size_t)((s - 1) * NBATCH + b_out) * HID + j_out]);
      float r = sigm(pre_ir + acc[0] + bR);
      float z = sigm(pre_iz + acc[1] + bZ);
      float n = tanh_fast(pre_in + r * (acc[2] + bN));
      float hnew = (1.0f - z) * n + z * hp;

      unsigned bits = (unsigned)f2h(hnew);
      unsigned hi = __shfl_down(bits, 16);
      if (jj_even) {
        unsigned packed = (bits & 0xffffu) | (hi << 16);
        __hip_atomic_store((unsigned*)(ys0f + (size_t)(s * NBATCH + b_out) * HID + j_out),
                           packed, __ATOMIC_RELAXED, __HIP_MEMORY_SCOPE_AGENT);
      }
      asm volatile("s_waitcnt vmcnt(0)" ::: "memory");
      if (l == 0)
        __hip_atomic_store(&flg0[(bid * 2 + nt) * 16], (unsigned)(s + 1),
                           __ATOMIC_RELAXED, __HIP_MEMORY_SCOPE_AGENT);
    }

    // ---------- merged role 1+2: layer-1 step t1 = s-1 ----------
    if (isHH && s >= 1) {
      const int t1 = s - 1;
      // input-side: Wih1 . ys0f[t1]
      const char* hb0 = (const char*)(ys0f + (size_t)t1 * NBATCH * HID) + bfragOff;
      f32x4 ai0 = {}, ai1 = {};
#pragma unroll
      for (int c = 0; c < 32; c += 2) {
        f16x8 bf0 = *(const f16x8*)(hb0 + c * 64);
        f16x8 bf1 = *(const f16x8*)(hb0 + c * 64 + 64);
        ai0 = __builtin_amdgcn_mfma_f32_16x16x32_f16(afA[c], bf0, ai0, 0, 0, 0);
        ai1 = __builtin_amdgcn_mfma_f32_16x16x32_f16(afA[c + 1], bf1, ai1, 0, 0, 0);
      }
      f32x4 acci = ai0 + ai1;
      // hidden-side: Whh1 . h1[t1-1]
      const _Float16* hs1 = (t1 == 0) ? h1i : (ys1f + (size_t)(t1 - 1) * NBATCH * HID);
      const char* hb1 = (const char*)hs1 + bfragOff;
      f32x4 ah0 = {}, ah1 = {};
#pragma unroll
      for (int c = 0; c < 32; c += 2) {
        f16x8 bf0 = *(const f16x8*)(hb1 + c * 64);
        f16x8 bf1 = *(const f16x8*)(hb1 + c * 64 + 64);
        ah0 = __builtin_amdgcn_mfma_f32_16x16x32_f16(afB[c], bf0, ah0, 0, 0, 0);
        ah1 = __builtin_amdgcn_mfma_f32_16x16x32_f16(afB[c + 1], bf1, ah1, 0, 0, 0);
      }
      f32x4 acch = ah0 + ah1;

      float hp = (float)((t1 == 0) ? h1i[b_out * HID + j_out]
                                   : ys1f[(size_t)((t1 - 1) * NBATCH + b_out) * HID + j_out]);
      float r = sigm(acci[0] + biR + acch[0] + bR);
      float z = sigm(acci[1] + biZ + acch[1] + bZ);
      float n = tanh_fast(acci[2] + biN + r * (acch[2] + bN));
      float hnew = (1.0f - z) * n + z * hp;

      unsigned bits = (unsigned)f2h(hnew);
      unsigned hi = __shfl_down(bits, 16);
      if (jj_even) {
        unsigned packed = (bits & 0xffffu) | (hi << 16);
        __hip_atomic_store((unsigned*)(ys1f + (size_t)(t1 * NBATCH + b_out) * HID + j_out),
                           packed, __ATOMIC_RELAXED, __HIP_MEMORY_SCOPE_AGENT);
      }
      asm volatile("s_waitcnt vmcnt(0)" ::: "memory");
      if (l == 0)
        __hip_atomic_store(&flg1[(bid * 2 + nt) * 16], (unsigned)s,   // = t1+1
                           __ATOMIC_RELAXED, __HIP_MEMORY_SCOPE_AGENT);
    }
  }

  // sequencer: final epoch1 = 128 so tail tiles (mh=63) unlock everywhere
  if (isSeq) {
    for (;;) {
      unsigned m1 = 0xffffffffu;
#pragma unroll
      for (int i = 0; i < 8; ++i) {
        unsigned v = __hip_atomic_load(flg1 + l * 128 + i * 16, __ATOMIC_RELAXED, __HIP_MEMORY_SCOPE_AGENT);
        m1 = v < m1 ? v : m1;
      }
      if (__all(m1 >= (unsigned)T_SEQ)) break;
      if (!try_gemm()) __builtin_amdgcn_s_sleep(2);
    }
    __hip_atomic_store(epoch1 + l * 16, (unsigned)T_SEQ, __ATOMIC_RELAXED, __HIP_MEMORY_SCOPE_AGENT);
    asm volatile("" ::: "memory");
  }

  // ---- drain remaining logits tiles ----
  while (tileT < NTILE) {
    if (kc == 0) {
      int mh = tileT / 500;
      unsigned need = (unsigned)(2 * mh + 2);
      while (__hip_atomic_load(ep1, __ATOMIC_RELAXED, __HIP_MEMORY_SCOPE_AGENT) < need)
        __builtin_amdgcn_s_sleep(8);
      asm volatile("" ::: "memory");
    }
    gemm_chunk();
  }
}

// ---------------- host ----------------
extern "C" void kernel_launch(void* const* d_in, const int* in_sizes, int n_in,
                              void* d_out, int out_size, void* d_ws, size_t ws_size,
                              hipStream_t stream)
{
  const int*   inputs = (const int*)d_in[0];
  const float* hidden = (const float*)d_in[2];
  const float* table  = (const float*)d_in[3];
  const float* Wih0   = (const float*)d_in[4];
  const float* Whh0   = (const float*)d_in[5];
  const float* bih0   = (const float*)d_in[6];
  const float* bhh0   = (const float*)d_in[7];
  const float* Wih1   = (const float*)d_in[8];
  const float* Whh1   = (const float*)d_in[9];
  const float* bih1   = (const float*)d_in[10];
  const float* bhh1   = (const float*)d_in[11];
  const float* Wout   = (const float*)d_in[12];
  const float* bout   = (const float*)d_in[13];
  float* out = (float*)d_out;

  char* ws = (char*)d_ws;
  size_t off = 0;
  auto alloc = [&](size_t bytes) {
    void* p = ws + off;
    off += (bytes + 255) & ~(size_t)255;
    return p;
  };
  float*     gi0  = (float*)alloc((size_t)4096 * 3072 * 4);
  _Float16*  ys0f = (_Float16*)alloc((size_t)4096 * 1024 * 2);
  _Float16*  ys1f = (_Float16*)alloc((size_t)4096 * 1024 * 2);
  short*     A0   = (short*)alloc((size_t)4096 * 512 * 2);
  short*     B0   = (short*)alloc((size_t)3072 * 512 * 2);
  short*     B2   = (short*)alloc((size_t)32000 * 1024 * 2);
  _Float16*  hcat = (_Float16*)alloc((size_t)2 * 32 * 1024 * 2);
  _Float16*  h0i  = hcat;
  _Float16*  h1i  = hcat + 32 * 1024;
  unsigned int* flg0   = (unsigned int*)alloc(512 * 16 * 4);
  unsigned int* flg1   = (unsigned int*)alloc(512 * 16 * 4);
  unsigned int* epoch0 = (unsigned int*)alloc(64 * 16 * 4);
  unsigned int* epoch1 = (unsigned int*)alloc(64 * 16 * 4);

  // zero sync state (contiguous 18432 dwords from flg0)
  k_zero<<<72, 256, 0, stream>>>(flg0, 18432);

  // conversions
  k_f32_to_f16<<<1024, 256, 0, stream>>>((const float4*)Wih0, (ushort4*)B0, 3072 * 512 / 4);
  k_f32_to_f16<<<2048, 256, 0, stream>>>((const float4*)Wout, (ushort4*)B2, 32000 * 1024 / 4);
  k_f32_to_f16<<<64, 256, 0, stream>>>((const float4*)hidden, (ushort4*)hcat, 2 * 32 * 1024 / 4);
  k_embed<<<2048, 256, 0, stream>>>(inputs, table, (ushort4*)A0);

  // layer-0 input-side gates: gi0 = A0 @ Wih0^T + bih0   [4096,3072]
  dim3 g0(32, 24);
  k_gemm_bt<<<g0, 256, 0, stream>>>(A0, B0, gi0, bih0, 4096, 3072, 512, 0);

  // fused recurrence + logits (cooperative, 256 blocks x 256 threads)
  {
    void* kargs[] = {
      (void*)&gi0, (void*)&Whh0, (void*)&bhh0,
      (void*)&Wih1, (void*)&bih1, (void*)&Whh1, (void*)&bhh1,
      (void*)&h0i, (void*)&h1i, (void*)&ys0f, (void*)&ys1f,
      (void*)&B2, (void*)&bout, (void*)&out,
      (void*)&flg0, (void*)&flg1, (void*)&epoch0, (void*)&epoch1
    };
    hipError_t e = hipLaunchCooperativeKernel((const void*)k_gru_fused, dim3(NBLK),
                                              dim3(256), kargs, 0, stream);
    if (e != hipSuccess) {
      (void)hipGetLastError();
      k_gru_fused<<<dim3(NBLK), dim3(256), 0, stream>>>(
          gi0, Whh0, bhh0, Wih1, bih1, Whh1, bhh1,
          h0i, h1i, ys0f, ys1f, B2, bout, out,
          flg0, flg1, epoch0, epoch1);
    }
  }
}

// Round 10
// 1782.757 us; speedup vs baseline: 1.8686x; 1.8686x over previous
//
#include <hip/hip_runtime.h>
#include <hip/hip_bf16.h>
#include <stdint.h>

#define T_SEQ 128
#define NBATCH 32
#define EMBED 512
#define HID 1024
#define NVOCAB 32000
#define NBLK 256   // recurrence worker blocks

typedef float f32x4 __attribute__((ext_vector_type(4)));
typedef _Float16 f16x8 __attribute__((ext_vector_type(8)));

__device__ __forceinline__ unsigned short f2h(float f) {
  _Float16 h = (_Float16)f;
  return __builtin_bit_cast(unsigned short, h);
}
__device__ __forceinline__ float sigm(float x) {
  return 1.0f / (1.0f + __expf(-x));
}
__device__ __forceinline__ float tanh_fast(float x) {
  return 2.0f / (1.0f + __expf(-2.0f * x)) - 1.0f;
}

// ---------------- zero the sync state ----------------
__global__ void k_zero(unsigned int* __restrict__ p, int n) {
  int i = blockIdx.x * blockDim.x + threadIdx.x;
  if (i < n) p[i] = 0;
}

// ---------------- f32 -> f16 convert (vectorized, grid-stride) ----------------
__global__ void k_f32_to_f16(const float4* __restrict__ in,
                             ushort4* __restrict__ out, int n4) {
  int i = blockIdx.x * blockDim.x + threadIdx.x;
  int stride = gridDim.x * blockDim.x;
  for (; i < n4; i += stride) {
    float4 v = in[i];
    ushort4 o;
    o.x = f2h(v.x); o.y = f2h(v.y); o.z = f2h(v.z); o.w = f2h(v.w);
    out[i] = o;
  }
}

// ------------- embedding gather -> A0 f16 [4096][512], row m = t*32+b -------------
__global__ void k_embed(const int* __restrict__ tok, const float* __restrict__ table,
                        ushort4* __restrict__ A0) {
  int tid = blockIdx.x * 256 + threadIdx.x;   // 4096*128 threads total
  int m = tid >> 7, kq = tid & 127;
  int b = m & 31, t = m >> 5;
  int tk = tok[b * T_SEQ + t];
  float4 v = *(const float4*)(table + (size_t)tk * EMBED + kq * 4);
  ushort4 o;
  o.x = f2h(v.x); o.y = f2h(v.y); o.z = f2h(v.z); o.w = f2h(v.w);
  A0[tid] = o;
}

// ---------------- f16 MFMA GEMM: C[M,N] = A[M,K] * B[N,K]^T (+bias) ----------------
// 128x128 tile, BK=64, 4 waves, reg-staged LDS (round-4-exact, proven fastest here).
// permute=1: output row m=(t*32+b) is written to row (b*128+t)  [for logits layout]
#define BM 128
#define BN 128
#define BKK 64

__global__ __launch_bounds__(256) void k_gemm_bt(
    const short* __restrict__ A,   // [M,K] f16 bits
    const short* __restrict__ B,   // [N,K] f16 bits
    float* __restrict__ C,
    const float* __restrict__ bias, // [N]
    int M, int N, int K, int permute)
{
  __shared__ __align__(16) short As[BM * BKK];
  __shared__ __align__(16) short Bs[BN * BKK];
  const int tid = threadIdx.x;
  const int w = tid >> 6, l = tid & 63;
  const int wr = w >> 1, wc = w & 1;
  const int bm = blockIdx.x * BM, bn = blockIdx.y * BN;
  const int l15 = l & 15, lkg = l >> 4;

  f32x4 acc[4][4] = {};

  for (int kt = 0; kt < K; kt += BKK) {
#pragma unroll
    for (int p = 0; p < 4; ++p) {
      int idx = p * 2048 + tid * 8;          // element index in [128*64)
      int r = idx >> 6, c = idx & 63;
      *(f16x8*)&As[idx] = *(const f16x8*)&A[(size_t)(bm + r) * K + kt + c];
      *(f16x8*)&Bs[idx] = *(const f16x8*)&B[(size_t)(bn + r) * K + kt + c];
    }
    __syncthreads();

#pragma unroll
    for (int ks = 0; ks < 2; ++ks) {
      f16x8 af[4], bfr[4];
#pragma unroll
      for (int mi = 0; mi < 4; ++mi)
        af[mi] = *(const f16x8*)&As[(wr * 64 + mi * 16 + l15) * BKK + ks * 32 + lkg * 8];
#pragma unroll
      for (int ni = 0; ni < 4; ++ni)
        bfr[ni] = *(const f16x8*)&Bs[(wc * 64 + ni * 16 + l15) * BKK + ks * 32 + lkg * 8];
#pragma unroll
      for (int mi = 0; mi < 4; ++mi)
#pragma unroll
        for (int ni = 0; ni < 4; ++ni)
          acc[mi][ni] = __builtin_amdgcn_mfma_f32_16x16x32_f16(
              af[mi], bfr[ni], acc[mi][ni], 0, 0, 0);
    }
    __syncthreads();
  }

  const int lr = lkg * 4;
#pragma unroll
  for (int mi = 0; mi < 4; ++mi) {
#pragma unroll
    for (int ni = 0; ni < 4; ++ni) {
      int col = bn + wc * 64 + ni * 16 + l15;
      float bv = bias ? bias[col] : 0.0f;
#pragma unroll
      for (int j = 0; j < 4; ++j) {
        int row = bm + wr * 64 + mi * 16 + lr + j;
        int orow = permute ? ((row & 31) * T_SEQ + (row >> 5)) : row;
        C[(size_t)orow * N + col] = acc[mi][ni][j] + bv;
      }
    }
  }
}

// ---------------- fused 2-layer GRU recurrence (persistent, flag-synced) ----------------
// 256 blocks x 384 threads. Block owns j in [4*bid, 4*bid+4); wave w: role=w>>1
// (0: W_hh0 @ s, 1: W_ih1 @ s-1, 2: W_hh1 @ s-2), nt=w&1 (batch half).
// HYBRID of the two proven designs (round-9 decision):
//  - round-4 direct polling: every block's wave0 polls ALL 512 per-wave flags
//    (8 flg0 + 8 flg1 per lane, 64B-padded) for the block-level needs; no
//    sequencer hop (round 7/8 showed the hop costs ~1.6us/iter).
//  - round-7 per-wave immediate publish: each role wave does sc1 h-store ->
//    s_waitcnt vmcnt(0) -> lane0 sc1 flag store, right after ITS compute. No
//    bottom barrier: the single top __syncthreads + parity-double-buffered
//    bufIH gives all required ordering (correctness proven in rounds 7/8).
__global__ __launch_bounds__(384, 2) void k_gru_fused(
    const float* __restrict__ gi0,    // [128][32][3072] (includes b_ih0)
    const float* __restrict__ Whh0,   // [3072][1024]
    const float* __restrict__ bhh0,   // [3072]
    const float* __restrict__ Wih1,   // [3072][1024]
    const float* __restrict__ bih1,   // [3072]
    const float* __restrict__ Whh1,   // [3072][1024]
    const float* __restrict__ bhh1,   // [3072]
    const _Float16* __restrict__ h0i, // [32][1024]
    const _Float16* __restrict__ h1i, // [32][1024]
    _Float16* __restrict__ ys0f,      // [128][32][1024]
    _Float16* __restrict__ ys1f,      // [128][32][1024]
    unsigned int* flg0,               // [512*16] per-wave flag at (bid*2+nt)*16
    unsigned int* flg1)               // [512*16]
{
  __shared__ float bufIH[2][3][2][64];  // [parity][gate][nt][lane]

  const int tid = threadIdx.x;
  const int l = tid & 63;
  const int w = tid >> 6;
  const int bid = blockIdx.x;
  const int role = w >> 1, nt = w & 1;
  const int j0 = bid * 4;

  // A-fragment (operand) decode
  const int row16 = l & 15;
  const int jjr = row16 >> 2, gate = row16 & 3;
  const int koct = l >> 4;

  // output (C/D) decode
  const int b_out = nt * 16 + (l & 15);
  const int j_out = j0 + (l >> 4);
  const int jj_even = (((l >> 4) & 1) == 0);

  // ---- load W slice into registers as f16 A-fragments ----
  const float* Wsrc = (role == 0) ? Whh0 : ((role == 1) ? Wih1 : Whh1);
  f16x8 af[32];
  if (gate < 3) {
    const float* wrow = Wsrc + (size_t)(gate * HID + j0 + jjr) * HID;
#pragma unroll
    for (int c = 0; c < 32; ++c) {
      float4 p0 = *(const float4*)(wrow + c * 32 + koct * 8);
      float4 p1 = *(const float4*)(wrow + c * 32 + koct * 8 + 4);
      f16x8 v = { (_Float16)p0.x, (_Float16)p0.y, (_Float16)p0.z, (_Float16)p0.w,
                  (_Float16)p1.x, (_Float16)p1.y, (_Float16)p1.z, (_Float16)p1.w };
      af[c] = v;
    }
  } else {
#pragma unroll
    for (int c = 0; c < 32; ++c) {
      f16x8 z = { (_Float16)0.f, (_Float16)0.f, (_Float16)0.f, (_Float16)0.f,
                  (_Float16)0.f, (_Float16)0.f, (_Float16)0.f, (_Float16)0.f };
      af[c] = z;
    }
  }

  // ---- per-lane bias preloads ----
  float bR = 0.f, bZ = 0.f, bN = 0.f, biR = 0.f, biZ = 0.f, biN = 0.f;
  if (role == 0) {
    bR = bhh0[j_out]; bZ = bhh0[HID + j_out]; bN = bhh0[2 * HID + j_out];
  } else if (role == 2) {
    bR = bhh1[j_out]; bZ = bhh1[HID + j_out]; bN = bhh1[2 * HID + j_out];
    biR = bih1[j_out]; biZ = bih1[HID + j_out]; biN = bih1[2 * HID + j_out];
  }

  // per-lane byte offset into a [32][1024] f16 slab for B-fragment loads
  const int bfragOff = b_out * 2048 + koct * 16;

  for (int s = 0; s <= T_SEQ + 1; ++s) {
    // ---- prefetch flag-independent gi0 values (role 0) ----
    float pre_ir = 0.f, pre_iz = 0.f, pre_in = 0.f;
    if (role == 0 && s < T_SEQ) {
      const float* gib = gi0 + (size_t)(s * NBATCH + b_out) * 3072 + j_out;
      pre_ir = gib[0]; pre_iz = gib[HID]; pre_in = gib[2 * HID];
    }

    // ---- block-level wait: wave0 polls all 512 padded per-wave flags ----
    {
      unsigned need0 = (s >= 1 && s <= T_SEQ) ? (unsigned)s : 0u;   // ys0f[s-1] ready
      unsigned need1 = (s >= 3) ? (unsigned)(s - 2) : 0u;           // ys1f[s-3] ready
      if (w == 0 && (need0 | need1) != 0u) {
        const unsigned* f0 = flg0 + l * 128;   // lane l covers flag idx l*8..l*8+7
        const unsigned* f1 = flg1 + l * 128;
        for (;;) {
          unsigned m0 = 0xffffffffu, m1 = 0xffffffffu;
          if (need0) {
#pragma unroll
            for (int i = 0; i < 8; ++i) {
              unsigned v = __hip_atomic_load(f0 + i * 16, __ATOMIC_RELAXED, __HIP_MEMORY_SCOPE_AGENT);
              m0 = v < m0 ? v : m0;
            }
          }
          if (need1) {
#pragma unroll
            for (int i = 0; i < 8; ++i) {
              unsigned v = __hip_atomic_load(f1 + i * 16, __ATOMIC_RELAXED, __HIP_MEMORY_SCOPE_AGENT);
              m1 = v < m1 ? v : m1;
            }
          }
          if (__all(m0 >= need0 && m1 >= need1)) break;
          __builtin_amdgcn_s_sleep(1);
        }
        asm volatile("" ::: "memory");
      }
    }
    __syncthreads();   // gates the block on wave0's wait; orders bufIH parity handoff

    // ---------- role 0: layer-0 step t = s ----------
    if (role == 0 && s < T_SEQ) {
      const _Float16* hsrc = (s == 0) ? h0i : (ys0f + (size_t)(s - 1) * NBATCH * HID);
      const char* hb = (const char*)hsrc + bfragOff;
      f32x4 acc0 = {}, acc1 = {};
#pragma unroll
      for (int c = 0; c < 32; c += 2) {
        f16x8 bf0 = *(const f16x8*)(hb + c * 64);
        f16x8 bf1 = *(const f16x8*)(hb + c * 64 + 64);
        acc0 = __builtin_amdgcn_mfma_f32_16x16x32_f16(af[c], bf0, acc0, 0, 0, 0);
        acc1 = __builtin_amdgcn_mfma_f32_16x16x32_f16(af[c + 1], bf1, acc1, 0, 0, 0);
      }
      f32x4 acc = acc0 + acc1;

      float hp = (float)((s == 0) ? h0i[b_out * HID + j_out]
                                  : ys0f[(size_t)((s - 1) * NBATCH + b_out) * HID + j_out]);
      float r = sigm(pre_ir + acc[0] + bR);
      float z = sigm(pre_iz + acc[1] + bZ);
      float n = tanh_fast(pre_in + r * (acc[2] + bN));
      float hnew = (1.0f - z) * n + z * hp;

      unsigned bits = (unsigned)f2h(hnew);
      unsigned hi = __shfl_down(bits, 16);
      if (jj_even) {
        unsigned packed = (bits & 0xffffu) | (hi << 16);
        __hip_atomic_store((unsigned*)(ys0f + (size_t)(s * NBATCH + b_out) * HID + j_out),
                           packed, __ATOMIC_RELAXED, __HIP_MEMORY_SCOPE_AGENT);
      }
      // per-wave immediate publish: h at coherence point, then flag
      asm volatile("s_waitcnt vmcnt(0)" ::: "memory");
      if (l == 0)
        __hip_atomic_store(&flg0[(bid * 2 + nt) * 16], (unsigned)(s + 1),
                           __ATOMIC_RELAXED, __HIP_MEMORY_SCOPE_AGENT);
    }

    // ---------- role 1: layer-1 input gates for t1 = s-1 -> bufIH[s&1] ----------
    if (role == 1 && s >= 1 && s <= T_SEQ) {
      const _Float16* hsrc = ys0f + (size_t)(s - 1) * NBATCH * HID;
      const char* hb = (const char*)hsrc + bfragOff;
      f32x4 acc0 = {}, acc1 = {};
#pragma unroll
      for (int c = 0; c < 32; c += 2) {
        f16x8 bf0 = *(const f16x8*)(hb + c * 64);
        f16x8 bf1 = *(const f16x8*)(hb + c * 64 + 64);
        acc0 = __builtin_amdgcn_mfma_f32_16x16x32_f16(af[c], bf0, acc0, 0, 0, 0);
        acc1 = __builtin_amdgcn_mfma_f32_16x16x32_f16(af[c + 1], bf1, acc1, 0, 0, 0);
      }
      f32x4 acc = acc0 + acc1;
      bufIH[s & 1][0][nt][l] = acc[0];
      bufIH[s & 1][1][nt][l] = acc[1];
      bufIH[s & 1][2][nt][l] = acc[2];
    }

    // ---------- role 2: layer-1 hidden + combine for t1 = s-2 ----------
    if (role == 2 && s >= 2) {
      const int t1 = s - 2;
      const _Float16* hsrc = (t1 == 0) ? h1i : (ys1f + (size_t)(t1 - 1) * NBATCH * HID);
      const char* hb = (const char*)hsrc + bfragOff;
      f32x4 acc0 = {}, acc1 = {};
#pragma unroll
      for (int c = 0; c < 32; c += 2) {
        f16x8 bf0 = *(const f16x8*)(hb + c * 64);
        f16x8 bf1 = *(const f16x8*)(hb + c * 64 + 64);
        acc0 = __builtin_amdgcn_mfma_f32_16x16x32_f16(af[c], bf0, acc0, 0, 0, 0);
        acc1 = __builtin_amdgcn_mfma_f32_16x16x32_f16(af[c + 1], bf1, acc1, 0, 0, 0);
      }
      f32x4 acc = acc0 + acc1;

      const int par = (s - 1) & 1;
      float ihR = bufIH[par][0][nt][l] + biR;
      float ihZ = bufIH[par][1][nt][l] + biZ;
      float ihN = bufIH[par][2][nt][l] + biN;
      float hp = (float)((t1 == 0) ? h1i[b_out * HID + j_out]
                                   : ys1f[(size_t)((t1 - 1) * NBATCH + b_out) * HID + j_out]);
      float r = sigm(ihR + acc[0] + bR);
      float z = sigm(ihZ + acc[1] + bZ);
      float n = tanh_fast(ihN + r * (acc[2] + bN));
      float hnew = (1.0f - z) * n + z * hp;

      unsigned bits = (unsigned)f2h(hnew);
      unsigned hi = __shfl_down(bits, 16);
      if (jj_even) {
        unsigned packed = (bits & 0xffffu) | (hi << 16);
        __hip_atomic_store((unsigned*)(ys1f + (size_t)(t1 * NBATCH + b_out) * HID + j_out),
                           packed, __ATOMIC_RELAXED, __HIP_MEMORY_SCOPE_AGENT);
      }
      asm volatile("s_waitcnt vmcnt(0)" ::: "memory");
      if (l == 0)
        __hip_atomic_store(&flg1[(bid * 2 + nt) * 16], (unsigned)(s - 1),
                           __ATOMIC_RELAXED, __HIP_MEMORY_SCOPE_AGENT);
    }
    // no bottom barrier: per-wave publish; parity dbuf + top barrier give ordering
  }
}

// ---------------- host ----------------
extern "C" void kernel_launch(void* const* d_in, const int* in_sizes, int n_in,
                              void* d_out, int out_size, void* d_ws, size_t ws_size,
                              hipStream_t stream)
{
  const int*   inputs = (const int*)d_in[0];
  const float* hidden = (const float*)d_in[2];
  const float* table  = (const float*)d_in[3];
  const float* Wih0   = (const float*)d_in[4];
  const float* Whh0   = (const float*)d_in[5];
  const float* bih0   = (const float*)d_in[6];
  const float* bhh0   = (const float*)d_in[7];
  const float* Wih1   = (const float*)d_in[8];
  const float* Whh1   = (const float*)d_in[9];
  const float* bih1   = (const float*)d_in[10];
  const float* bhh1   = (const float*)d_in[11];
  const float* Wout   = (const float*)d_in[12];
  const float* bout   = (const float*)d_in[13];
  float* out = (float*)d_out;

  char* ws = (char*)d_ws;
  size_t off = 0;
  auto alloc = [&](size_t bytes) {
    void* p = ws + off;
    off += (bytes + 255) & ~(size_t)255;
    return p;
  };
  float*     gi0  = (float*)alloc((size_t)4096 * 3072 * 4);       // 48 MB
  _Float16*  ys0f = (_Float16*)alloc((size_t)4096 * 1024 * 2);    // 8 MB
  _Float16*  ys1f = (_Float16*)alloc((size_t)4096 * 1024 * 2);    // 8 MB
  short*     A0   = (short*)alloc((size_t)4096 * 512 * 2);
  short*     B0   = (short*)alloc((size_t)3072 * 512 * 2);
  short*     B2   = (short*)alloc((size_t)32000 * 1024 * 2);      // 64 MB
  _Float16*  hcat = (_Float16*)alloc((size_t)2 * 32 * 1024 * 2);
  _Float16*  h0i  = hcat;
  _Float16*  h1i  = hcat + 32 * 1024;
  unsigned int* flg0 = (unsigned int*)alloc(512 * 16 * 4);  // 32 KB (64B-padded)
  unsigned int* flg1 = (unsigned int*)alloc(512 * 16 * 4);  // 32 KB

  // zero sync state (contiguous 16384 dwords from flg0)
  k_zero<<<64, 256, 0, stream>>>(flg0, 16384);

  // conversions
  k_f32_to_f16<<<1024, 256, 0, stream>>>((const float4*)Wih0, (ushort4*)B0, 3072 * 512 / 4);
  k_f32_to_f16<<<2048, 256, 0, stream>>>((const float4*)Wout, (ushort4*)B2, 32000 * 1024 / 4);
  k_f32_to_f16<<<64, 256, 0, stream>>>((const float4*)hidden, (ushort4*)hcat, 2 * 32 * 1024 / 4);
  k_embed<<<2048, 256, 0, stream>>>(inputs, table, (ushort4*)A0);

  // layer-0 input-side gates: gi0 = A0 @ Wih0^T + bih0   [4096,3072]
  dim3 g0(32, 24);
  k_gemm_bt<<<g0, 256, 0, stream>>>(A0, B0, gi0, bih0, 4096, 3072, 512, 0);

  // fused 2-layer recurrence. Grid MUST be <= 256 for cooperative launch
  // (257 fails validation silently -> kernel no-op; rounds 5/6). Fall back to
  // a plain launch if the cooperative launch is rejected.
  {
    void* kargs[] = {
      (void*)&gi0, (void*)&Whh0, (void*)&bhh0,
      (void*)&Wih1, (void*)&bih1, (void*)&Whh1, (void*)&bhh1,
      (void*)&h0i, (void*)&h1i, (void*)&ys0f, (void*)&ys1f,
      (void*)&flg0, (void*)&flg1
    };
    hipError_t e = hipLaunchCooperativeKernel((const void*)k_gru_fused, dim3(NBLK),
                                              dim3(384), kargs, 0, stream);
    if (e != hipSuccess) {
      (void)hipGetLastError();   // clear error state; fall back to plain launch
      k_gru_fused<<<dim3(NBLK), dim3(384), 0, stream>>>(
          gi0, Whh0, bhh0, Wih1, bih1, Whh1, bhh1,
          h0i, h1i, ys0f, ys1f, flg0, flg1);
    }
  }

  // output projection: logits[b,s,v]  (row permutation folded into epilogue)
  dim3 g2(32, 250);
  k_gemm_bt<<<g2, 256, 0, stream>>>((const short*)ys1f, B2, out, bout, 4096, 32000, 1024, 1);
}

// Round 11
// 1469.847 us; speedup vs baseline: 2.2664x; 1.2129x over previous
//
#include <hip/hip_runtime.h>
#include <hip/hip_bf16.h>
#include <stdint.h>

#define T_SEQ 128
#define NBATCH 32
#define EMBED 512
#define HID 1024
#define NVOCAB 32000
#define NBLK 256   // recurrence worker blocks

typedef float f32x4 __attribute__((ext_vector_type(4)));
typedef _Float16 f16x8 __attribute__((ext_vector_type(8)));

__device__ __forceinline__ unsigned short f2h(float f) {
  _Float16 h = (_Float16)f;
  return __builtin_bit_cast(unsigned short, h);
}
__device__ __forceinline__ float sigm(float x) {
  return 1.0f / (1.0f + __expf(-x));
}
__device__ __forceinline__ float tanh_fast(float x) {
  return 2.0f / (1.0f + __expf(-2.0f * x)) - 1.0f;
}
__device__ __forceinline__ unsigned umin4(unsigned a, unsigned b, unsigned c, unsigned d) {
  unsigned x = a < b ? a : b;
  unsigned y = c < d ? c : d;
  return x < y ? x : y;
}

// ---------------- zero the sync flags (512 uints) ----------------
__global__ void k_zero(unsigned int* __restrict__ p, int n) {
  int i = blockIdx.x * blockDim.x + threadIdx.x;
  if (i < n) p[i] = 0;
}

// ---------------- f32 -> f16 convert (vectorized, grid-stride) ----------------
__global__ void k_f32_to_f16(const float4* __restrict__ in,
                             ushort4* __restrict__ out, int n4) {
  int i = blockIdx.x * blockDim.x + threadIdx.x;
  int stride = gridDim.x * blockDim.x;
  for (; i < n4; i += stride) {
    float4 v = in[i];
    ushort4 o;
    o.x = f2h(v.x); o.y = f2h(v.y); o.z = f2h(v.z); o.w = f2h(v.w);
    out[i] = o;
  }
}

// ------------- embedding gather -> A0 f16 [4096][512], row m = t*32+b -------------
__global__ void k_embed(const int* __restrict__ tok, const float* __restrict__ table,
                        ushort4* __restrict__ A0) {
  int tid = blockIdx.x * 256 + threadIdx.x;   // 4096*128 threads total
  int m = tid >> 7, kq = tid & 127;
  int b = m & 31, t = m >> 5;
  int tk = tok[b * T_SEQ + t];
  float4 v = *(const float4*)(table + (size_t)tk * EMBED + kq * 4);
  ushort4 o;
  o.x = f2h(v.x); o.y = f2h(v.y); o.z = f2h(v.z); o.w = f2h(v.w);
  A0[tid] = o;
}

// ---------------- f16 MFMA GEMM: 128x128 tile, reg-staged (proven; gi0 only) ----------------
#define BM 128
#define BN 128
#define BKK 64

__global__ __launch_bounds__(256) void k_gemm_bt(
    const short* __restrict__ A,   // [M,K] f16 bits
    const short* __restrict__ B,   // [N,K] f16 bits
    float* __restrict__ C,
    const float* __restrict__ bias, // [N]
    int M, int N, int K, int permute)
{
  __shared__ __align__(16) short As[BM * BKK];
  __shared__ __align__(16) short Bs[BN * BKK];
  const int tid = threadIdx.x;
  const int w = tid >> 6, l = tid & 63;
  const int wr = w >> 1, wc = w & 1;
  const int bm = blockIdx.x * BM, bn = blockIdx.y * BN;
  const int l15 = l & 15, lkg = l >> 4;

  f32x4 acc[4][4] = {};

  for (int kt = 0; kt < K; kt += BKK) {
#pragma unroll
    for (int p = 0; p < 4; ++p) {
      int idx = p * 2048 + tid * 8;          // element index in [128*64)
      int r = idx >> 6, c = idx & 63;
      *(f16x8*)&As[idx] = *(const f16x8*)&A[(size_t)(bm + r) * K + kt + c];
      *(f16x8*)&Bs[idx] = *(const f16x8*)&B[(size_t)(bn + r) * K + kt + c];
    }
    __syncthreads();

#pragma unroll
    for (int ks = 0; ks < 2; ++ks) {
      f16x8 af[4], bfr[4];
#pragma unroll
      for (int mi = 0; mi < 4; ++mi)
        af[mi] = *(const f16x8*)&As[(wr * 64 + mi * 16 + l15) * BKK + ks * 32 + lkg * 8];
#pragma unroll
      for (int ni = 0; ni < 4; ++ni)
        bfr[ni] = *(const f16x8*)&Bs[(wc * 64 + ni * 16 + l15) * BKK + ks * 32 + lkg * 8];
#pragma unroll
      for (int mi = 0; mi < 4; ++mi)
#pragma unroll
        for (int ni = 0; ni < 4; ++ni)
          acc[mi][ni] = __builtin_amdgcn_mfma_f32_16x16x32_f16(
              af[mi], bfr[ni], acc[mi][ni], 0, 0, 0);
    }
    __syncthreads();
  }

  const int lr = lkg * 4;
#pragma unroll
  for (int mi = 0; mi < 4; ++mi) {
#pragma unroll
    for (int ni = 0; ni < 4; ++ni) {
      int col = bn + wc * 64 + ni * 16 + l15;
      float bv = bias ? bias[col] : 0.0f;
#pragma unroll
      for (int j = 0; j < 4; ++j) {
        int row = bm + wr * 64 + mi * 16 + lr + j;
        int orow = permute ? ((row & 31) * T_SEQ + (row >> 5)) : row;
        C[(size_t)orow * N + col] = acc[mi][ni][j] + bv;
      }
    }
  }
}

// ============ 256^2 8-phase f16 GEMM (logits): C = A[M,K] x B[N,K]^T, permuted rows + bias ============
// 8 waves (2M x 4N), BK=64, 128KiB LDS (2 dbuf x 32KB x {A,B}), global_load_lds staging
// with G4 swizzle (cb ^= (row&7)<<4; pre-swizzled source + swizzled ds_read), counted
// vmcnt(4) at tile boundaries (A-halves staged 2 tiles ahead, B-halves 1 tile ahead),
// raw s_barrier + sched_barrier, setprio around MFMA clusters.
#define LK 1024
#define GNT 16          // K / 64

__global__ __launch_bounds__(512, 2) void k_gemm256(
    const short* __restrict__ A,    // [4096][1024] f16 (ys1f)
    const short* __restrict__ B,    // [32000][1024] f16 (W_out)
    float* __restrict__ C,          // [4096][32000] f32, rows permuted
    const float* __restrict__ bias, // [32000]
    int N)                          // 32000 (C stride)
{
  __shared__ __align__(16) short As[2][256 * 64];   // 64 KB
  __shared__ __align__(16) short Bs[2][256 * 64];   // 64 KB

  const int tid = threadIdx.x;
  const int l = tid & 63, wid = tid >> 6;
  const int wm = wid >> 2, wn = wid & 3;
  const int l15 = l & 15, lkg = l >> 4;
  const int bm = blockIdx.x * 256, bn = blockIdx.y * 256;

  f32x4 acc[8][4] = {};

  // stage one half-tile (128 rows x 64 cols f16 = 16KB): 2 gloads/thread, linear LDS,
  // source column pre-swizzled so swizzled ds_read sees the right data (rule #21).
  auto stage_half = [&](int kt, int op, int half) {
    const short* G = op ? B : A;
    const int base_row = (op ? bn : bm) + half * 128;
    char* L = (char*)(op ? Bs[kt & 1] : As[kt & 1]) + half * 128 * 64 * 2;
#pragma unroll
    for (int p = 0; p < 2; ++p) {
      int chunk = p * 512 + tid;           // 16B chunk in half-tile
      int Lbyte = chunk * 16;
      int r = Lbyte >> 7;                  // row (128B per row)
      int cb = Lbyte & 127;
      int scb = cb ^ ((r & 7) << 4);       // swizzled source col-byte (involution)
      const char* src = (const char*)&G[(size_t)(base_row + r) * LK + kt * 64] + scb;
      char* dst = L + (p * 512 + wid * 64) * 16;   // wave-uniform; HW adds lane*16
      __builtin_amdgcn_global_load_lds(
          (const __attribute__((address_space(1))) void*)src,
          (__attribute__((address_space(3))) void*)dst, 16, 0, 0);
    }
  };

  // ---- prologue: stage A(t0), B(t0), A(t1); allow A(t1) in flight ----
  stage_half(0, 0, 0); stage_half(0, 0, 1);
  stage_half(0, 1, 0); stage_half(0, 1, 1);
  stage_half(1, 0, 0); stage_half(1, 0, 1);
  asm volatile("s_waitcnt vmcnt(4)" ::: "memory");
  __builtin_amdgcn_sched_barrier(0);
  __builtin_amdgcn_s_barrier();
  __builtin_amdgcn_sched_barrier(0);

  for (int kt = 0; kt < GNT; ++kt) {
    const char* bufA = (const char*)As[kt & 1];
    const char* bufB = (const char*)Bs[kt & 1];
    f16x8 afr[8][2];
    f16x8 bfr[2][2];

    // swizzled ds_read helpers (byte addr = row*128 + (colbyte ^ ((row&7)<<4)))
#define RD_A(mi_, ks_) \
    (*(const f16x8*)(bufA + ((wm * 128 + (mi_) * 16 + l15) * 128 + \
        (((ks_) * 64 + lkg * 16) ^ (((wm * 128 + (mi_) * 16 + l15) & 7) << 4)))))
#define RD_B(ni_, ks_) \
    (*(const f16x8*)(bufB + ((wn * 64 + (ni_) * 16 + l15) * 128 + \
        (((ks_) * 64 + lkg * 16) ^ (((wn * 64 + (ni_) * 16 + l15) & 7) << 4)))))

#define MFMA_QUAD(MI0, NI0) \
    __builtin_amdgcn_s_setprio(1); \
    _Pragma("unroll") \
    for (int ks = 0; ks < 2; ++ks) \
      _Pragma("unroll") \
      for (int i = 0; i < 4; ++i) \
        _Pragma("unroll") \
        for (int j = 0; j < 2; ++j) \
          acc[(MI0) + i][(NI0) + j] = __builtin_amdgcn_mfma_f32_16x16x32_f16( \
              afr[(MI0) + i][ks], bfr[j][ks], acc[(MI0) + i][(NI0) + j], 0, 0, 0); \
    __builtin_amdgcn_s_setprio(0);

#define PHASE_BARS() \
    __builtin_amdgcn_s_barrier(); __builtin_amdgcn_sched_barrier(0);

    // ---- q0: read A(mi0-3) + B(ni0-1); stage B(kt+1, half0); MFMA quad (0,0) ----
#pragma unroll
    for (int i = 0; i < 4; ++i) { afr[i][0] = RD_A(i, 0); afr[i][1] = RD_A(i, 1); }
#pragma unroll
    for (int j = 0; j < 2; ++j) { bfr[j][0] = RD_B(j, 0); bfr[j][1] = RD_B(j, 1); }
    if (kt + 1 < GNT) stage_half(kt + 1, 1, 0);
    PHASE_BARS();
    MFMA_QUAD(0, 0);
    PHASE_BARS();

    // ---- q1: read A(mi4-7); stage B(kt+1, half1); MFMA quad (4,0) ----
#pragma unroll
    for (int i = 0; i < 4; ++i) { afr[4 + i][0] = RD_A(4 + i, 0); afr[4 + i][1] = RD_A(4 + i, 1); }
    if (kt + 1 < GNT) stage_half(kt + 1, 1, 1);
    PHASE_BARS();
    MFMA_QUAD(4, 0);
    PHASE_BARS();

    // ---- q2: read B(ni2-3); stage A(kt+2, half0); MFMA quad (0,2) ----
#pragma unroll
    for (int j = 0; j < 2; ++j) { bfr[j][0] = RD_B(2 + j, 0); bfr[j][1] = RD_B(2 + j, 1); }
    if (kt + 2 < GNT) stage_half(kt + 2, 0, 0);
    PHASE_BARS();
    MFMA_QUAD(0, 2);
    PHASE_BARS();

    // ---- q3: stage A(kt+2, half1); MFMA quad (4,2) ----
    if (kt + 2 < GNT) stage_half(kt + 2, 0, 1);
    PHASE_BARS();
    MFMA_QUAD(4, 2);
    PHASE_BARS();

    // ---- tile boundary: counted vmcnt (A(kt+2) halves may stay in flight) ----
    if (kt + 1 < GNT) {
      if (kt + 2 < GNT) {
        asm volatile("s_waitcnt vmcnt(4)" ::: "memory");
      } else {
        asm volatile("s_waitcnt vmcnt(0)" ::: "memory");
      }
      __builtin_amdgcn_sched_barrier(0);
      __builtin_amdgcn_s_barrier();
      __builtin_amdgcn_sched_barrier(0);
    }
#undef RD_A
#undef RD_B
#undef MFMA_QUAD
#undef PHASE_BARS
  }

  // ---- epilogue: permuted rows + bias (same C/D mapping as proven kernel) ----
  const int lr = lkg * 4;
#pragma unroll
  for (int mi = 0; mi < 8; ++mi) {
#pragma unroll
    for (int ni = 0; ni < 4; ++ni) {
      int col = bn + wn * 64 + ni * 16 + l15;
      float bv = bias[col];
#pragma unroll
      for (int j = 0; j < 4; ++j) {
        int row = bm + wm * 128 + mi * 16 + lr + j;
        int orow = (row & 31) * T_SEQ + (row >> 5);
        C[(size_t)orow * N + col] = acc[mi][ni][j] + bv;
      }
    }
  }
}

// ---------------- fused 2-layer GRU recurrence (round-4 EXACT: best measured, 1072us) ----------------
__global__ __launch_bounds__(384, 2) void k_gru_fused(
    const float* __restrict__ gi0,    // [128][32][3072] (includes b_ih0)
    const float* __restrict__ Whh0,   // [3072][1024]
    const float* __restrict__ bhh0,   // [3072]
    const float* __restrict__ Wih1,   // [3072][1024]
    const float* __restrict__ bih1,   // [3072]
    const float* __restrict__ Whh1,   // [3072][1024]
    const float* __restrict__ bhh1,   // [3072]
    const _Float16* __restrict__ h0i, // [32][1024]
    const _Float16* __restrict__ h1i, // [32][1024]
    _Float16* __restrict__ ys0f,      // [128][32][1024]
    _Float16* __restrict__ ys1f,      // [128][32][1024]
    unsigned int* flg0,               // [256]
    unsigned int* flg1)               // [256]
{
  __shared__ float bufIH[2][3][2][64];  // [parity][gate][nt][lane]

  const int tid = threadIdx.x;
  const int l = tid & 63;
  const int w = tid >> 6;
  const int role = w >> 1, nt = w & 1;
  const int bid = blockIdx.x;
  const int j0 = bid * 4;

  const int row16 = l & 15;
  const int jjr = row16 >> 2, gate = row16 & 3;
  const int koct = l >> 4;

  const int b_out = nt * 16 + (l & 15);
  const int j_out = j0 + (l >> 4);
  const int jj_even = (((l >> 4) & 1) == 0);

  const float* Wsrc = (role == 0) ? Whh0 : ((role == 1) ? Wih1 : Whh1);
  f16x8 af[32];
  if (gate < 3) {
    const float* wrow = Wsrc + (size_t)(gate * HID + j0 + jjr) * HID;
#pragma unroll
    for (int c = 0; c < 32; ++c) {
      float4 p0 = *(const float4*)(wrow + c * 32 + koct * 8);
      float4 p1 = *(const float4*)(wrow + c * 32 + koct * 8 + 4);
      f16x8 v = { (_Float16)p0.x, (_Float16)p0.y, (_Float16)p0.z, (_Float16)p0.w,
                  (_Float16)p1.x, (_Float16)p1.y, (_Float16)p1.z, (_Float16)p1.w };
      af[c] = v;
    }
  } else {
#pragma unroll
    for (int c = 0; c < 32; ++c) {
      f16x8 z = { (_Float16)0.f, (_Float16)0.f, (_Float16)0.f, (_Float16)0.f,
                  (_Float16)0.f, (_Float16)0.f, (_Float16)0.f, (_Float16)0.f };
      af[c] = z;
    }
  }

  float bR = 0.f, bZ = 0.f, bN = 0.f, biR = 0.f, biZ = 0.f, biN = 0.f;
  if (role == 0) {
    bR = bhh0[j_out]; bZ = bhh0[HID + j_out]; bN = bhh0[2 * HID + j_out];
  } else if (role == 2) {
    bR = bhh1[j_out]; bZ = bhh1[HID + j_out]; bN = bhh1[2 * HID + j_out];
    biR = bih1[j_out]; biZ = bih1[HID + j_out]; biN = bih1[2 * HID + j_out];
  }

  const int bfragOff = b_out * 2048 + koct * 16;

  for (int s = 0; s <= T_SEQ + 1; ++s) {
    float pre_ir = 0.f, pre_iz = 0.f, pre_in = 0.f;
    if (role == 0 && s < T_SEQ) {
      const float* gib = gi0 + (size_t)(s * NBATCH + b_out) * 3072 + j_out;
      pre_ir = gib[0]; pre_iz = gib[HID]; pre_in = gib[2 * HID];
    }

    if (w == 0) {
      unsigned need0 = (s >= 1 && s <= T_SEQ) ? (unsigned)s : 0u;       // ys0f[s-1]
      unsigned need1 = (s >= 3) ? (unsigned)(s - 2) : 0u;               // ys1f[s-3]
      if ((need0 | need1) != 0u) {
        const unsigned* f0 = flg0 + l * 4;
        const unsigned* f1 = flg1 + l * 4;
        for (;;) {
          unsigned m0 = 0xffffffffu, m1 = 0xffffffffu;
          if (need0) {
            unsigned a0 = __hip_atomic_load(f0 + 0, __ATOMIC_RELAXED, __HIP_MEMORY_SCOPE_AGENT);
            unsigned a1 = __hip_atomic_load(f0 + 1, __ATOMIC_RELAXED, __HIP_MEMORY_SCOPE_AGENT);
            unsigned a2 = __hip_atomic_load(f0 + 2, __ATOMIC_RELAXED, __HIP_MEMORY_SCOPE_AGENT);
            unsigned a3 = __hip_atomic_load(f0 + 3, __ATOMIC_RELAXED, __HIP_MEMORY_SCOPE_AGENT);
            m0 = umin4(a0, a1, a2, a3);
          }
          if (need1) {
            unsigned a0 = __hip_atomic_load(f1 + 0, __ATOMIC_RELAXED, __HIP_MEMORY_SCOPE_AGENT);
            unsigned a1 = __hip_atomic_load(f1 + 1, __ATOMIC_RELAXED, __HIP_MEMORY_SCOPE_AGENT);
            unsigned a2 = __hip_atomic_load(f1 + 2, __ATOMIC_RELAXED, __HIP_MEMORY_SCOPE_AGENT);
            unsigned a3 = __hip_atomic_load(f1 + 3, __ATOMIC_RELAXED, __HIP_MEMORY_SCOPE_AGENT);
            m1 = umin4(a0, a1, a2, a3);
          }
          if (__all(m0 >= need0 && m1 >= need1)) break;
          __builtin_amdgcn_s_sleep(1);
        }
        asm volatile("" ::: "memory");
      }
    }
    __syncthreads();

    // ---------- role 0: layer-0 step t = s ----------
    if (role == 0 && s < T_SEQ) {
      const _Float16* hsrc = (s == 0) ? h0i : (ys0f + (size_t)(s - 1) * NBATCH * HID);
      const char* hb = (const char*)hsrc + bfragOff;
      f32x4 acc0 = {}, acc1 = {};
#pragma unroll
      for (int c = 0; c < 32; c += 2) {
        f16x8 bf0 = *(const f16x8*)(hb + c * 64);
        f16x8 bf1 = *(const f16x8*)(hb + c * 64 + 64);
        acc0 = __builtin_amdgcn_mfma_f32_16x16x32_f16(af[c], bf0, acc0, 0, 0, 0);
        acc1 = __builtin_amdgcn_mfma_f32_16x16x32_f16(af[c + 1], bf1, acc1, 0, 0, 0);
      }
      f32x4 acc = acc0 + acc1;

      float hp = (float)((s == 0) ? h0i[b_out * HID + j_out]
                                  : ys0f[(size_t)((s - 1) * NBATCH + b_out) * HID + j_out]);
      float r = sigm(pre_ir + acc[0] + bR);
      float z = sigm(pre_iz + acc[1] + bZ);
      float n = tanh_fast(pre_in + r * (acc[2] + bN));
      float hnew = (1.0f - z) * n + z * hp;

      unsigned bits = (unsigned)f2h(hnew);
      unsigned hi = __shfl_down(bits, 16);
      if (jj_even) {
        unsigned packed = (bits & 0xffffu) | (hi << 16);
        __hip_atomic_store((unsigned*)(ys0f + (size_t)(s * NBATCH + b_out) * HID + j_out),
                           packed, __ATOMIC_RELAXED, __HIP_MEMORY_SCOPE_AGENT);
      }
    }

    // ---------- role 1: layer-1 input gates for t1 = s-1 -> bufIH[s&1] ----------
    if (role == 1 && s >= 1 && s <= T_SEQ) {
      const _Float16* hsrc = ys0f + (size_t)(s - 1) * NBATCH * HID;
      const char* hb = (const char*)hsrc + bfragOff;
      f32x4 acc0 = {}, acc1 = {};
#pragma unroll
      for (int c = 0; c < 32; c += 2) {
        f16x8 bf0 = *(const f16x8*)(hb + c * 64);
        f16x8 bf1 = *(const f16x8*)(hb + c * 64 + 64);
        acc0 = __builtin_amdgcn_mfma_f32_16x16x32_f16(af[c], bf0, acc0, 0, 0, 0);
        acc1 = __builtin_amdgcn_mfma_f32_16x16x32_f16(af[c + 1], bf1, acc1, 0, 0, 0);
      }
      f32x4 acc = acc0 + acc1;
      bufIH[s & 1][0][nt][l] = acc[0];
      bufIH[s & 1][1][nt][l] = acc[1];
      bufIH[s & 1][2][nt][l] = acc[2];
    }

    // ---------- role 2: layer-1 hidden + combine for t1 = s-2 ----------
    if (role == 2 && s >= 2) {
      const int t1 = s - 2;
      const _Float16* hsrc = (t1 == 0) ? h1i : (ys1f + (size_t)(t1 - 1) * NBATCH * HID);
      const char* hb = (const char*)hsrc + bfragOff;
      f32x4 acc0 = {}, acc1 = {};
#pragma unroll
      for (int c = 0; c < 32; c += 2) {
        f16x8 bf0 = *(const f16x8*)(hb + c * 64);
        f16x8 bf1 = *(const f16x8*)(hb + c * 64 + 64);
        acc0 = __builtin_amdgcn_mfma_f32_16x16x32_f16(af[c], bf0, acc0, 0, 0, 0);
        acc1 = __builtin_amdgcn_mfma_f32_16x16x32_f16(af[c + 1], bf1, acc1, 0, 0, 0);
      }
      f32x4 acc = acc0 + acc1;

      const int par = (s - 1) & 1;
      float ihR = bufIH[par][0][nt][l] + biR;
      float ihZ = bufIH[par][1][nt][l] + biZ;
      float ihN = bufIH[par][2][nt][l] + biN;
      float hp = (float)((t1 == 0) ? h1i[b_out * HID + j_out]
                                   : ys1f[(size_t)((t1 - 1) * NBATCH + b_out) * HID + j_out]);
      float r = sigm(ihR + acc[0] + bR);
      float z = sigm(ihZ + acc[1] + bZ);
      float n = tanh_fast(ihN + r * (acc[2] + bN));
      float hnew = (1.0f - z) * n + z * hp;

      unsigned bits = (unsigned)f2h(hnew);
      unsigned hi = __shfl_down(bits, 16);
      if (jj_even) {
        unsigned packed = (bits & 0xffffu) | (hi << 16);
        __hip_atomic_store((unsigned*)(ys1f + (size_t)(t1 * NBATCH + b_out) * HID + j_out),
                           packed, __ATOMIC_RELAXED, __HIP_MEMORY_SCOPE_AGENT);
      }
    }

    __syncthreads();   // drains each wave's stores (vmcnt 0) + publishes bufIH

    if (tid == 0) {
      if (s < T_SEQ)
        __hip_atomic_store(&flg0[bid], (unsigned)(s + 1), __ATOMIC_RELAXED, __HIP_MEMORY_SCOPE_AGENT);
      if (s >= 2)
        __hip_atomic_store(&flg1[bid], (unsigned)(s - 1), __ATOMIC_RELAXED, __HIP_MEMORY_SCOPE_AGENT);
    }
  }
}

// ---------------- host ----------------
extern "C" void kernel_launch(void* const* d_in, const int* in_sizes, int n_in,
                              void* d_out, int out_size, void* d_ws, size_t ws_size,
                              hipStream_t stream)
{
  const int*   inputs = (const int*)d_in[0];
  const float* hidden = (const float*)d_in[2];
  const float* table  = (const float*)d_in[3];
  const float* Wih0   = (const float*)d_in[4];
  const float* Whh0   = (const float*)d_in[5];
  const float* bih0   = (const float*)d_in[6];
  const float* bhh0   = (const float*)d_in[7];
  const float* Wih1   = (const float*)d_in[8];
  const float* Whh1   = (const float*)d_in[9];
  const float* bih1   = (const float*)d_in[10];
  const float* bhh1   = (const float*)d_in[11];
  const float* Wout   = (const float*)d_in[12];
  const float* bout   = (const float*)d_in[13];
  float* out = (float*)d_out;

  char* ws = (char*)d_ws;
  size_t off = 0;
  auto alloc = [&](size_t bytes) {
    void* p = ws + off;
    off += (bytes + 255) & ~(size_t)255;
    return p;
  };
  float*     gi0  = (float*)alloc((size_t)4096 * 3072 * 4);       // 48 MB
  _Float16*  ys0f = (_Float16*)alloc((size_t)4096 * 1024 * 2);    // 8 MB
  _Float16*  ys1f = (_Float16*)alloc((size_t)4096 * 1024 * 2);    // 8 MB
  short*     A0   = (short*)alloc((size_t)4096 * 512 * 2);
  short*     B0   = (short*)alloc((size_t)3072 * 512 * 2);
  short*     B2   = (short*)alloc((size_t)32000 * 1024 * 2);      // 64 MB
  _Float16*  hcat = (_Float16*)alloc((size_t)2 * 32 * 1024 * 2);
  _Float16*  h0i  = hcat;
  _Float16*  h1i  = hcat + 32 * 1024;
  unsigned int* flg0 = (unsigned int*)alloc(256 * 4);
  unsigned int* flg1 = (unsigned int*)alloc(256 * 4);

  // zero sync flags first (stream-ordered before the recurrence; covers flg0+flg1)
  k_zero<<<1, 512, 0, stream>>>(flg0, 512);

  // conversions
  k_f32_to_f16<<<1024, 256, 0, stream>>>((const float4*)Wih0, (ushort4*)B0, 3072 * 512 / 4);
  k_f32_to_f16<<<2048, 256, 0, stream>>>((const float4*)Wout, (ushort4*)B2, 32000 * 1024 / 4);
  k_f32_to_f16<<<64, 256, 0, stream>>>((const float4*)hidden, (ushort4*)hcat, 2 * 32 * 1024 / 4);
  k_embed<<<2048, 256, 0, stream>>>(inputs, table, (ushort4*)A0);

  // layer-0 input-side gates: gi0 = A0 @ Wih0^T + bih0   [4096,3072]
  dim3 g0(32, 24);
  k_gemm_bt<<<g0, 256, 0, stream>>>(A0, B0, gi0, bih0, 4096, 3072, 512, 0);

  // fused 2-layer recurrence (round-4-exact protocol; grid must stay <= 256)
  {
    void* kargs[] = {
      (void*)&gi0, (void*)&Whh0, (void*)&bhh0,
      (void*)&Wih1, (void*)&bih1, (void*)&Whh1, (void*)&bhh1,
      (void*)&h0i, (void*)&h1i, (void*)&ys0f, (void*)&ys1f,
      (void*)&flg0, (void*)&flg1
    };
    hipError_t e = hipLaunchCooperativeKernel((const void*)k_gru_fused, dim3(NBLK),
                                              dim3(384), kargs, 0, stream);
    if (e != hipSuccess) {
      (void)hipGetLastError();   // clear error state; fall back to plain launch
      k_gru_fused<<<dim3(NBLK), dim3(384), 0, stream>>>(
          gi0, Whh0, bhh0, Wih1, bih1, Whh1, bhh1,
          h0i, h1i, ys0f, ys1f, flg0, flg1);
    }
  }

  // output projection: logits[b,s,v] via 256^2 8-phase kernel
  dim3 g2(16, 125);
  k_gemm256<<<g2, 512, 0, stream>>>((const short*)ys1f, B2, out, bout, NVOCAB);
}